// Round 7
// baseline (101.372 us; speedup 1.0000x reference)
//
#include <hip/hip_runtime.h>
#include <hip/hip_bf16.h>
#include <stdint.h>

// Problem constants (B=8, C=512, H=W=32, N=4)
constexpr int BN = 32;     // B*N batch-heads
constexpr int Cn = 128;    // channels per head
constexpr int L  = 1024;   // H*W
constexpr int CC = 512;    // C
constexpr int BB = 8;      // B

typedef __bf16 bf16x8 __attribute__((ext_vector_type(8)));
typedef float  f32x4  __attribute__((ext_vector_type(4)));

__device__ inline unsigned short f2bf(float f) {
    unsigned int x = __float_as_uint(f);
    x += 0x7fffu + ((x >> 16) & 1u);   // round-to-nearest-even
    return (unsigned short)(x >> 16);
}
__device__ inline __bf16 bfbits(unsigned short u) {
    union { unsigned short s; __bf16 b; } cv; cv.s = u; return cv.b;
}

// async global->LDS, 16B per lane (dest = wave-uniform base + lane*16)
__device__ inline void gl_lds16(const void* g, void* l) {
    typedef __attribute__((address_space(1))) const unsigned int GU;
    typedef __attribute__((address_space(3))) unsigned int LU;
    __builtin_amdgcn_global_load_lds((GU*)g, (LU*)l, 16, 0, 0);
}

// ---------------------------------------------------------------------------
// Kernel 0: split the four 128x128 weight matrices into bf16 hi/lo pairs.
//   whi/wlo layout: [mat 0..3][o][c] flat (mat: 0=w1 1=w2 2=w3 3=w4).
// ---------------------------------------------------------------------------
__global__ __launch_bounds__(256)
void wsplit_kernel(const float* __restrict__ w1, const float* __restrict__ w2,
                   const float* __restrict__ w3, const float* __restrict__ w4,
                   unsigned short* __restrict__ whi, unsigned short* __restrict__ wlo)
{
    int idx = (blockIdx.x * 256 + threadIdx.x) * 4;   // 0..65532
    int mat = idx >> 14;
    int off = idx & 16383;
    const float* w = (mat == 0) ? w1 : (mat == 1) ? w2 : (mat == 2) ? w3 : w4;
    float4 v = *(const float4*)&w[off];
    ushort4 hi, lo;
    hi.x = f2bf(v.x); lo.x = f2bf(v.x - __uint_as_float((unsigned)hi.x << 16));
    hi.y = f2bf(v.y); lo.y = f2bf(v.y - __uint_as_float((unsigned)hi.y << 16));
    hi.z = f2bf(v.z); lo.z = f2bf(v.z - __uint_as_float((unsigned)hi.z << 16));
    hi.w = f2bf(v.w); lo.w = f2bf(v.w - __uint_as_float((unsigned)hi.w << 16));
    *(ushort4*)&whi[idx] = hi;
    *(ushort4*)&wlo[idx] = lo;
}

// ---------------------------------------------------------------------------
// Kernel 1 (v4): LDS-free MFMA projections, occupancy-first.
//   P[l][o] = sum_c w[o][c] * x[c][l] via 3-pass split bf16 MFMA
//   (w_hi*x_hi + w_lo*x_hi + w_hi*x_lo), f32 acc, bf16 store in the attn
//   chunk-swizzle format (chunk j of row l at j^(l&7)).
// Block = (bn, src, l-strip of 64, o-half of 64); 4 waves = l-quarters of 16.
// B-frags (x columns) loaded DIRECTLY from global into registers: per lane
// (r16=j=l, g) frag kk holds x[kk*32+g*8+t][l] -- 8 stride-L scalar f32
// loads, split hi/lo in VALU. No LDS, no __syncthreads.
// acc[2 mats][4 og] = 32 VGPR; ~16 waves/CU at VGPR<=128.
// grid = 32*2*16*2 = 2048.
// ---------------------------------------------------------------------------
__global__ __launch_bounds__(256, 4)
void proj_kernel(const float* __restrict__ first, const float* __restrict__ second,
                 const unsigned short* __restrict__ whi,
                 const unsigned short* __restrict__ wlo,
                 unsigned short* __restrict__ outP)
{
    const int p     = blockIdx.x;
    const int oh    = p & 1;           // o-half (64)
    const int strip = (p >> 1) & 15;   // 64-row l strip
    const int src   = (p >> 5) & 1;
    const int bn    = p >> 6;

    const float* x = (src == 0 ? first : second) + (size_t)bn * Cn * L + strip * 64;
    const int m0 = src;       // 0=w1/Kt or 1=w2/Qt
    const int m1 = 2 + src;   // 2=w3/V1t or 3=w4/V2t
    const unsigned short* WH[2] = { whi + m0 * 16384, whi + m1 * 16384 };
    const unsigned short* WL[2] = { wlo + m0 * 16384, wlo + m1 * 16384 };
    unsigned short* Pm[2] = { outP + (size_t)(m0 * BN + bn) * (L * Cn),
                              outP + (size_t)(m1 * BN + bn) * (L * Cn) };

    const int tid  = threadIdx.x;
    const int lane = tid & 63;
    const int wv   = tid >> 6;    // wave = l-quarter (16 rows)
    const int r16  = lane & 15;
    const int g    = lane >> 4;

    const int lloc = wv * 16 + r16;          // l within strip (0..63)

    // ---- load x columns straight into B-frag sources (32 scalar f32) ----
    float xv[4][8];
    #pragma unroll
    for (int kk = 0; kk < 4; ++kk)
        #pragma unroll
        for (int j = 0; j < 8; ++j)
            xv[kk][j] = x[(size_t)(kk * 32 + g * 8 + j) * L + lloc];

    // ---- split to hi/lo bf16 frags ----
    bf16x8 bh[4], bl[4];
    #pragma unroll
    for (int kk = 0; kk < 4; ++kk)
        #pragma unroll
        for (int j = 0; j < 8; ++j) {
            unsigned short h = f2bf(xv[kk][j]);
            bh[kk][j] = bfbits(h);
            bl[kk][j] = bfbits(f2bf(xv[kk][j] - __uint_as_float((unsigned)h << 16)));
        }

    f32x4 acc[2][4];              // [mat][og] = 32 VGPR
    #pragma unroll
    for (int m = 0; m < 2; ++m)
        #pragma unroll
        for (int a = 0; a < 4; ++a) acc[m][a] = (f32x4){0.f, 0.f, 0.f, 0.f};

    #pragma unroll
    for (int kk = 0; kk < 4; ++kk) {
        const int c = kk * 32 + g * 8;
        #pragma unroll
        for (int mat = 0; mat < 2; ++mat)
            #pragma unroll
            for (int og = 0; og < 4; ++og) {
                const int o = oh * 64 + og * 16 + r16;
                bf16x8 ah = *(const bf16x8*)&WH[mat][o * 128 + c];
                bf16x8 al = *(const bf16x8*)&WL[mat][o * 128 + c];
                f32x4 a = acc[mat][og];
                a = __builtin_amdgcn_mfma_f32_16x16x32_bf16(ah, bh[kk], a, 0, 0, 0);
                a = __builtin_amdgcn_mfma_f32_16x16x32_bf16(al, bh[kk], a, 0, 0, 0);
                a = __builtin_amdgcn_mfma_f32_16x16x32_bf16(ah, bl[kk], a, 0, 0, 0);
                acc[mat][og] = a;
            }
    }

    // ---- store P (bf16, attn swizzle: chunk j of row l at j^(l&7)) ----
    const int l = strip * 64 + lloc;
    #pragma unroll
    for (int mat = 0; mat < 2; ++mat)
        #pragma unroll
        for (int og = 0; og < 4; ++og) {
            int o0 = oh * 64 + og * 16 + g * 4;          // reg r -> o0+r
            f32x4 a = acc[mat][og];
            ushort4 st;
            st.x = f2bf(a.x); st.y = f2bf(a.y);
            st.z = f2bf(a.z); st.w = f2bf(a.w);
            int pos = (((o0 >> 3) ^ (l & 7)) << 3) | (o0 & 7);
            *(ushort4*)&Pm[mat][(size_t)l * 128 + pos] = st;
        }
}

// ---------------------------------------------------------------------------
// Kernel 2: MFMA attention with no-max softmax (shift 8), m-split in halves.
//   (unchanged)
// ---------------------------------------------------------------------------
__global__ __launch_bounds__(256, 2)
void attn_kernel(const unsigned short* __restrict__ Pb,
                 float* __restrict__ Dp, float* __restrict__ Rp)
{
    __shared__ char smem[2][2][16384];   // [buf][q/v2][64 rows * 256B]

    const int p   = blockIdx.x;          // 0..511
    const int xcd = p & 7;
    const int jj  = p >> 3;              // 0..63
    const int bn  = xcd * 4 + (jj & 3);  // all blocks of a bn on one XCD
    const int lt  = (jj >> 2) & 7;       // 0..7 (128-row l tile)
    const int mh  = jj >> 5;             // 0..1 (m half)

    const int tid  = threadIdx.x;
    const int lane = tid & 63;
    const int w    = tid >> 6;           // wave 0..3
    const int r16  = lane & 15;
    const int g    = lane >> 4;          // 0..3
    const int swz  = lane & 7;

    const size_t slab = (size_t)L * Cn;
    const unsigned short* Kt  = Pb + (size_t)(0 * BN + bn) * slab;
    const unsigned short* Qt  = Pb + (size_t)(1 * BN + bn) * slab;
    const unsigned short* V1t = Pb + (size_t)(2 * BN + bn) * slab;
    const unsigned short* V2t = Pb + (size_t)(3 * BN + bn) * slab;

    const int lbase = lt * 128;

    // A-frags for K and V1, kept in registers the whole kernel.
    bf16x8 ka[2][4], va[2][4];
    #pragma unroll
    for (int i = 0; i < 2; ++i)
        #pragma unroll
        for (int kk = 0; kk < 4; ++kk) {
            int row = lbase + w * 32 + i * 16 + r16;
            int cp = ((kk << 2) + g) ^ swz;           // swizzled chunk (row&7 == swz)
            ka[i][kk] = *(const bf16x8*)(Kt  + (size_t)row * 128 + cp * 8);
            va[i][kk] = *(const bf16x8*)(V1t + (size_t)row * 128 + cp * 8);
        }

    const f32x4 z = {0.f, 0.f, 0.f, 0.f};
    f32x4 Dv[2] = {z, z};
    f32x4 Rv[2] = {z, z};

    auto STAGE = [&](int buf, int t) {
        const int m0 = mh * 512 + t * 64;
        const char* qs = (const char*)Qt  + (size_t)m0 * 256;
        const char* vs = (const char*)V2t + (size_t)m0 * 256;
        char* qd = &smem[buf][0][0];
        char* vd = &smem[buf][1][0];
        #pragma unroll
        for (int it = 0; it < 4; ++it) {
            gl_lds16(qs + tid * 16 + it * 4096, qd + tid * 16 + it * 4096);
            gl_lds16(vs + tid * 16 + it * 4096, vd + tid * 16 + it * 4096);
        }
    };

    auto COMPUTE = [&](int buf) {
        const char* qb = &smem[buf][0][0];
        const char* vb = &smem[buf][1][0];
        #pragma unroll
        for (int cg = 0; cg < 4; ++cg) {
            const int brow = cg * 16 + r16;           // brow&7 == swz
            const int rbase = brow * 256;
            bf16x8 qf[4], vf[4];
            #pragma unroll
            for (int kk = 0; kk < 4; ++kk) {
                int off = rbase + ((((kk << 2) + g) ^ swz) << 4);
                qf[kk] = *(const bf16x8*)(qb + off);
                vf[kk] = *(const bf16x8*)(vb + off);
            }
            f32x4 s0 = z, s1 = z, u0 = z, u1 = z;
            #pragma unroll
            for (int kk = 0; kk < 4; ++kk) {
                s0 = __builtin_amdgcn_mfma_f32_16x16x32_bf16(ka[0][kk], qf[kk], s0, 0, 0, 0);
                s1 = __builtin_amdgcn_mfma_f32_16x16x32_bf16(ka[1][kk], qf[kk], s1, 0, 0, 0);
                u0 = __builtin_amdgcn_mfma_f32_16x16x32_bf16(va[0][kk], vf[kk], u0, 0, 0, 0);
                u1 = __builtin_amdgcn_mfma_f32_16x16x32_bf16(va[1][kk], vf[kk], u1, 0, 0, 0);
            }
            f32x4 e0, e1;
            e0.x = __expf(s0.x - 8.f); e0.y = __expf(s0.y - 8.f);
            e0.z = __expf(s0.z - 8.f); e0.w = __expf(s0.w - 8.f);
            e1.x = __expf(s1.x - 8.f); e1.y = __expf(s1.y - 8.f);
            e1.z = __expf(s1.z - 8.f); e1.w = __expf(s1.w - 8.f);
            Dv[0] += e0;      Dv[1] += e1;
            Rv[0] += e0 * u0; Rv[1] += e1 * u1;
        }
    };

    STAGE(0, 0);
    __syncthreads();                       // drains vmcnt before first compute
    for (int t = 0; t < 8; ++t) {
        if (t < 7) STAGE((t + 1) & 1, t + 1);   // loads in flight during compute
        COMPUTE(t & 1);
        __syncthreads();                   // drains vmcnt(0): next tile ready
    }

    // butterfly-sum D,R over the 16 lanes sharing each row group
    #pragma unroll
    for (int off = 8; off >= 1; off >>= 1) {
        #pragma unroll
        for (int i = 0; i < 2; ++i) {
            #pragma unroll
            for (int r = 0; r < 4; ++r) {
                Dv[i][r] += __shfl_xor(Dv[i][r], off);
                Rv[i][r] += __shfl_xor(Rv[i][r], off);
            }
        }
    }
    if (r16 == 0) {
        #pragma unroll
        for (int i = 0; i < 2; ++i)
            #pragma unroll
            for (int r = 0; r < 4; ++r) {
                int l = lbase + w * 32 + i * 16 + g * 4 + r;
                size_t idx = (size_t)mh * BN * L + (size_t)bn * L + l;
                Dp[idx] = Dv[i][r];
                Rp[idx] = Rv[i][r];
            }
    }
}

// ---------------------------------------------------------------------------
// Kernel 3: res = (R0+R1)/(D0+D1).  32768 elems -> 128 blocks x 256 thr.
// ---------------------------------------------------------------------------
__global__ __launch_bounds__(256)
void combine_kernel(const float* __restrict__ Dp, const float* __restrict__ Rp,
                    float* __restrict__ res)
{
    int i = blockIdx.x * 256 + threadIdx.x;
    float d = Dp[i] + Dp[BN * L + i];
    float r = Rp[i] + Rp[BN * L + i];
    res[i] = r / d;
}

// ---------------------------------------------------------------------------
// Kernel 4: out[b][o][hw] = relu( sum_n w5[o][n] * res[b*4+n][hw] )
// ---------------------------------------------------------------------------
__global__ __launch_bounds__(256)
void out_kernel(const float* __restrict__ res, const float* __restrict__ w5,
                float* __restrict__ out)
{
    const int blk = blockIdx.x;
    const int o = blk & 511;
    const int b = blk >> 9;
    const float4 wv = *(const float4*)&w5[o * 4];

    const float* r0 = res + (size_t)(b * 4 + 0) * L;
    const float* r1 = res + (size_t)(b * 4 + 1) * L;
    const float* r2 = res + (size_t)(b * 4 + 2) * L;
    const float* r3 = res + (size_t)(b * 4 + 3) * L;

    const int hw = threadIdx.x * 4;
    float4 a0 = *(const float4*)&r0[hw];
    float4 a1 = *(const float4*)&r1[hw];
    float4 a2 = *(const float4*)&r2[hw];
    float4 a3 = *(const float4*)&r3[hw];

    float4 ov;
    ov.x = fmaxf(0.f, wv.x * a0.x + wv.y * a1.x + wv.z * a2.x + wv.w * a3.x);
    ov.y = fmaxf(0.f, wv.x * a0.y + wv.y * a1.y + wv.z * a2.y + wv.w * a3.y);
    ov.z = fmaxf(0.f, wv.x * a0.z + wv.y * a1.z + wv.z * a2.z + wv.w * a3.z);
    ov.w = fmaxf(0.f, wv.x * a0.w + wv.y * a1.w + wv.z * a2.w + wv.w * a3.w);

    *(float4*)&out[(size_t)blk * 1024 + hw] = ov;
}

// ---------------------------------------------------------------------------
extern "C" void kernel_launch(void* const* d_in, const int* in_sizes, int n_in,
                              void* d_out, int out_size, void* d_ws, size_t ws_size,
                              hipStream_t stream)
{
    const float* first  = (const float*)d_in[0];
    const float* second = (const float*)d_in[1];
    const float* w1 = (const float*)d_in[2];
    const float* w2 = (const float*)d_in[3];
    const float* w3 = (const float*)d_in[4];
    const float* w4 = (const float*)d_in[5];
    const float* w5 = (const float*)d_in[6];
    float* out = (float*)d_out;

    const size_t projBytes = (size_t)4 * BN * L * Cn * sizeof(unsigned short); // 32 MB
    unsigned short* P = (unsigned short*)d_ws;
    float* Dp  = (float*)((char*)d_ws + projBytes);
    float* Rp  = Dp + 2 * BN * L;
    float* res = Rp + 2 * BN * L;
    unsigned short* whi = (unsigned short*)(res + BN * L);
    unsigned short* wlo = whi + 4 * 16384;

    wsplit_kernel<<<dim3(64), dim3(256), 0, stream>>>(w1, w2, w3, w4, whi, wlo);
    proj_kernel<<<dim3(2048), dim3(256), 0, stream>>>(first, second, whi, wlo, P);
    attn_kernel<<<dim3(512), dim3(256), 0, stream>>>(P, Dp, Rp);
    combine_kernel<<<dim3(BN * L / 256), dim3(256), 0, stream>>>(Dp, Rp, res);
    out_kernel<<<dim3(BB * CC), dim3(256), 0, stream>>>(res, w5, out);
}

// Round 8
// 63.346 us; speedup vs baseline: 1.6003x; 1.6003x over previous
//
#include <hip/hip_runtime.h>
#include <hip/hip_bf16.h>
#include <stdint.h>

// Problem constants (B=8, C=512, H=W=32, N=4)
constexpr int BN = 32;     // B*N batch-heads
constexpr int Cn = 128;    // channels per head
constexpr int L  = 1024;   // H*W
constexpr int CC = 512;    // C
constexpr int BB = 8;      // B

typedef __bf16 bf16x8 __attribute__((ext_vector_type(8)));
typedef float  f32x4  __attribute__((ext_vector_type(4)));
typedef unsigned short u16x8 __attribute__((ext_vector_type(8)));

__device__ inline unsigned short f2bf(float f) {
    unsigned int x = __float_as_uint(f);
    x += 0x7fffu + ((x >> 16) & 1u);   // round-to-nearest-even
    return (unsigned short)(x >> 16);
}

// async global->LDS, 16B per lane (dest = wave-uniform base + lane*16)
__device__ inline void gl_lds16(const void* g, void* l) {
    typedef __attribute__((address_space(1))) const unsigned int GU;
    typedef __attribute__((address_space(3))) unsigned int LU;
    __builtin_amdgcn_global_load_lds((GU*)g, (LU*)l, 16, 0, 0);
}

// ---------------------------------------------------------------------------
// Kernel 0: split the four 128x128 weight matrices into bf16 hi/lo pairs.
//   whi/wlo layout: [mat 0..3][o][c] flat (mat: 0=w1 1=w2 2=w3 3=w4).
// ---------------------------------------------------------------------------
__global__ __launch_bounds__(256)
void wsplit_kernel(const float* __restrict__ w1, const float* __restrict__ w2,
                   const float* __restrict__ w3, const float* __restrict__ w4,
                   unsigned short* __restrict__ whi, unsigned short* __restrict__ wlo)
{
    int idx = (blockIdx.x * 256 + threadIdx.x) * 4;   // 0..65532
    int mat = idx >> 14;
    int off = idx & 16383;
    const float* w = (mat == 0) ? w1 : (mat == 1) ? w2 : (mat == 2) ? w3 : w4;
    float4 v = *(const float4*)&w[off];
    ushort4 hi, lo;
    hi.x = f2bf(v.x); lo.x = f2bf(v.x - __uint_as_float((unsigned)hi.x << 16));
    hi.y = f2bf(v.y); lo.y = f2bf(v.y - __uint_as_float((unsigned)hi.y << 16));
    hi.z = f2bf(v.z); lo.z = f2bf(v.z - __uint_as_float((unsigned)hi.z << 16));
    hi.w = f2bf(v.w); lo.w = f2bf(v.w - __uint_as_float((unsigned)hi.w << 16));
    *(ushort4*)&whi[idx] = hi;
    *(ushort4*)&wlo[idx] = lo;
}

// ---------------------------------------------------------------------------
// Kernel 1 (v5): strip-pipelined MFMA projections, resident w-frags.
//   P[l][o] = sum_c w[o][c] * x[c][l] via 3-pass split bf16 MFMA
//   (w_hi*x_hi + w_lo*x_hi + w_hi*x_lo), f32 acc, bf16 store in the attn
//   chunk-swizzle format (chunk j of row l at j^(l&7)).
// grid = 256 = bn(32) x src(2) x l-quarter(4); 512 threads = 8 waves;
// wave = (mat, o-half, l-half). w-frags (one mat per wave) loaded ONCE into
// registers (32 x bf16x8 = 128 VGPR). 4 strips of 64 l, software-pipelined:
//   iter s: PREF(s+1) -> COMPUTE(strip s) -> STORE -> WRITE LDS(s+1) -> bar
// LDS: x hi/lo, 2 bufs, [64 l][128 c] bf16, 16B-chunk XOR swizzle = 64 KB.
// ---------------------------------------------------------------------------
__global__ __launch_bounds__(512, 2)
void proj_kernel(const float* __restrict__ first, const float* __restrict__ second,
                 const unsigned short* __restrict__ whi,
                 const unsigned short* __restrict__ wlo,
                 unsigned short* __restrict__ outP)
{
    __shared__ unsigned short xs[2][2][64 * 128];   // [part][buf][...] 64 KB

    const int p   = blockIdx.x;        // 0..255
    const int lq  = p & 3;             // 256-row l quarter
    const int src = (p >> 2) & 1;
    const int bn  = p >> 3;

    const float* x = (src == 0 ? first : second) + (size_t)bn * Cn * L + lq * 256;

    const int tid  = threadIdx.x;      // 0..511
    const int lane = tid & 63;
    const int wv   = tid >> 6;         // 0..7
    const int mat  = wv & 1;           // 0 -> w1/w2 slab, 1 -> w3/w4 slab
    const int oh   = (wv >> 1) & 1;    // o-half (64)
    const int lh   = wv >> 2;          // l-half (32) within strip
    const int r16  = lane & 15;
    const int g    = lane >> 4;

    const int mi = mat * 2 + src;      // matrix index 0..3
    const unsigned short* WHm = whi + mi * 16384;
    const unsigned short* WLm = wlo + mi * 16384;
    unsigned short* Pout = outP + (size_t)(mi * BN + bn) * (L * Cn);

    // ---- resident w-frags: [og][kk], loaded once (128 VGPR) ----
    bf16x8 ah[4][4], al[4][4];
    #pragma unroll
    for (int og = 0; og < 4; ++og)
        #pragma unroll
        for (int kk = 0; kk < 4; ++kk) {
            int o = oh * 64 + og * 16 + r16;
            int c = kk * 32 + g * 8;
            ah[og][kk] = *(const bf16x8*)&WHm[o * 128 + c];
            al[og][kk] = *(const bf16x8*)&WLm[o * 128 + c];
        }

    // ---- staging thread mapping: 512 thr cover 64 l x 128 c ----
    const int sl   = tid & 63;         // l within strip
    const int cblk = tid >> 6;         // 0..7 (16 c's each)

    float xf[16];
    auto PREF = [&](int s) {           // 16 coalesced scalar loads (256B/wave)
        const float* xb = x + s * 64 + sl;
        #pragma unroll
        for (int j = 0; j < 16; ++j)
            xf[j] = xb[(size_t)(cblk * 16 + j) * L];
    };
    auto WRITE = [&](int buf) {        // convert + swizzled 16B LDS writes
        #pragma unroll
        for (int half = 0; half < 2; ++half) {
            u16x8 hi, lo;
            #pragma unroll
            for (int j = 0; j < 8; ++j) {
                float v = xf[half * 8 + j];
                unsigned short h = f2bf(v);
                hi[j] = h;
                lo[j] = f2bf(v - __uint_as_float((unsigned)h << 16));
            }
            int chunk = cblk * 2 + half;          // 0..15
            int slot  = chunk ^ (sl & 15);
            int off   = sl * 128 + slot * 8;
            *(u16x8*)&xs[0][buf][off] = hi;
            *(u16x8*)&xs[1][buf][off] = lo;
        }
    };

    PREF(0);
    WRITE(0);
    __syncthreads();

    #pragma unroll
    for (int s = 0; s < 4; ++s) {
        const int buf = s & 1;
        if (s < 3) PREF(s + 1);        // next strip's loads in flight

        f32x4 acc[4][2];               // [og][lg] = 32 VGPR
        #pragma unroll
        for (int a = 0; a < 4; ++a)
            #pragma unroll
            for (int b = 0; b < 2; ++b) acc[a][b] = (f32x4){0.f, 0.f, 0.f, 0.f};

        #pragma unroll
        for (int kk = 0; kk < 4; ++kk) {
            bf16x8 bh[2], bl[2];
            #pragma unroll
            for (int lg = 0; lg < 2; ++lg) {
                int l = lh * 32 + lg * 16 + r16;
                int slot = ((kk << 2) + g) ^ (l & 15);
                bh[lg] = *(const bf16x8*)&xs[0][buf][l * 128 + slot * 8];
                bl[lg] = *(const bf16x8*)&xs[1][buf][l * 128 + slot * 8];
            }
            #pragma unroll
            for (int og = 0; og < 4; ++og)
                #pragma unroll
                for (int lg = 0; lg < 2; ++lg) {
                    f32x4 a = acc[og][lg];
                    a = __builtin_amdgcn_mfma_f32_16x16x32_bf16(ah[og][kk], bh[lg], a, 0, 0, 0);
                    a = __builtin_amdgcn_mfma_f32_16x16x32_bf16(al[og][kk], bh[lg], a, 0, 0, 0);
                    a = __builtin_amdgcn_mfma_f32_16x16x32_bf16(ah[og][kk], bl[lg], a, 0, 0, 0);
                    acc[og][lg] = a;
                }
        }

        // ---- store P strip (bf16, attn swizzle: chunk j of row l at j^(l&7)) ----
        #pragma unroll
        for (int og = 0; og < 4; ++og)
            #pragma unroll
            for (int lg = 0; lg < 2; ++lg) {
                int o0 = oh * 64 + og * 16 + g * 4;     // reg r -> o0+r
                int l  = lq * 256 + s * 64 + lh * 32 + lg * 16 + r16;
                f32x4 a = acc[og][lg];
                ushort4 st;
                st.x = f2bf(a.x); st.y = f2bf(a.y);
                st.z = f2bf(a.z); st.w = f2bf(a.w);
                int pos = (((o0 >> 3) ^ (l & 7)) << 3) | (o0 & 7);
                *(ushort4*)&Pout[(size_t)l * 128 + pos] = st;
            }

        if (s < 3) {
            WRITE(buf ^ 1);            // strip s+1 into the other buffer
            __syncthreads();
        }
    }
}

// ---------------------------------------------------------------------------
// Kernel 2: MFMA attention with no-max softmax (shift 8), m-split in halves.
//   (unchanged)
// ---------------------------------------------------------------------------
__global__ __launch_bounds__(256, 2)
void attn_kernel(const unsigned short* __restrict__ Pb,
                 float* __restrict__ Dp, float* __restrict__ Rp)
{
    __shared__ char smem[2][2][16384];   // [buf][q/v2][64 rows * 256B]

    const int p   = blockIdx.x;          // 0..511
    const int xcd = p & 7;
    const int jj  = p >> 3;              // 0..63
    const int bn  = xcd * 4 + (jj & 3);  // all blocks of a bn on one XCD
    const int lt  = (jj >> 2) & 7;       // 0..7 (128-row l tile)
    const int mh  = jj >> 5;             // 0..1 (m half)

    const int tid  = threadIdx.x;
    const int lane = tid & 63;
    const int w    = tid >> 6;           // wave 0..3
    const int r16  = lane & 15;
    const int g    = lane >> 4;          // 0..3
    const int swz  = lane & 7;

    const size_t slab = (size_t)L * Cn;
    const unsigned short* Kt  = Pb + (size_t)(0 * BN + bn) * slab;
    const unsigned short* Qt  = Pb + (size_t)(1 * BN + bn) * slab;
    const unsigned short* V1t = Pb + (size_t)(2 * BN + bn) * slab;
    const unsigned short* V2t = Pb + (size_t)(3 * BN + bn) * slab;

    const int lbase = lt * 128;

    // A-frags for K and V1, kept in registers the whole kernel.
    bf16x8 ka[2][4], va[2][4];
    #pragma unroll
    for (int i = 0; i < 2; ++i)
        #pragma unroll
        for (int kk = 0; kk < 4; ++kk) {
            int row = lbase + w * 32 + i * 16 + r16;
            int cp = ((kk << 2) + g) ^ swz;           // swizzled chunk (row&7 == swz)
            ka[i][kk] = *(const bf16x8*)(Kt  + (size_t)row * 128 + cp * 8);
            va[i][kk] = *(const bf16x8*)(V1t + (size_t)row * 128 + cp * 8);
        }

    const f32x4 z = {0.f, 0.f, 0.f, 0.f};
    f32x4 Dv[2] = {z, z};
    f32x4 Rv[2] = {z, z};

    auto STAGE = [&](int buf, int t) {
        const int m0 = mh * 512 + t * 64;
        const char* qs = (const char*)Qt  + (size_t)m0 * 256;
        const char* vs = (const char*)V2t + (size_t)m0 * 256;
        char* qd = &smem[buf][0][0];
        char* vd = &smem[buf][1][0];
        #pragma unroll
        for (int it = 0; it < 4; ++it) {
            gl_lds16(qs + tid * 16 + it * 4096, qd + tid * 16 + it * 4096);
            gl_lds16(vs + tid * 16 + it * 4096, vd + tid * 16 + it * 4096);
        }
    };

    auto COMPUTE = [&](int buf) {
        const char* qb = &smem[buf][0][0];
        const char* vb = &smem[buf][1][0];
        #pragma unroll
        for (int cg = 0; cg < 4; ++cg) {
            const int brow = cg * 16 + r16;           // brow&7 == swz
            const int rbase = brow * 256;
            bf16x8 qf[4], vf[4];
            #pragma unroll
            for (int kk = 0; kk < 4; ++kk) {
                int off = rbase + ((((kk << 2) + g) ^ swz) << 4);
                qf[kk] = *(const bf16x8*)(qb + off);
                vf[kk] = *(const bf16x8*)(vb + off);
            }
            f32x4 s0 = z, s1 = z, u0 = z, u1 = z;
            #pragma unroll
            for (int kk = 0; kk < 4; ++kk) {
                s0 = __builtin_amdgcn_mfma_f32_16x16x32_bf16(ka[0][kk], qf[kk], s0, 0, 0, 0);
                s1 = __builtin_amdgcn_mfma_f32_16x16x32_bf16(ka[1][kk], qf[kk], s1, 0, 0, 0);
                u0 = __builtin_amdgcn_mfma_f32_16x16x32_bf16(va[0][kk], vf[kk], u0, 0, 0, 0);
                u1 = __builtin_amdgcn_mfma_f32_16x16x32_bf16(va[1][kk], vf[kk], u1, 0, 0, 0);
            }
            f32x4 e0, e1;
            e0.x = __expf(s0.x - 8.f); e0.y = __expf(s0.y - 8.f);
            e0.z = __expf(s0.z - 8.f); e0.w = __expf(s0.w - 8.f);
            e1.x = __expf(s1.x - 8.f); e1.y = __expf(s1.y - 8.f);
            e1.z = __expf(s1.z - 8.f); e1.w = __expf(s1.w - 8.f);
            Dv[0] += e0;      Dv[1] += e1;
            Rv[0] += e0 * u0; Rv[1] += e1 * u1;
        }
    };

    STAGE(0, 0);
    __syncthreads();                       // drains vmcnt before first compute
    for (int t = 0; t < 8; ++t) {
        if (t < 7) STAGE((t + 1) & 1, t + 1);   // loads in flight during compute
        COMPUTE(t & 1);
        __syncthreads();                   // drains vmcnt(0): next tile ready
    }

    // butterfly-sum D,R over the 16 lanes sharing each row group
    #pragma unroll
    for (int off = 8; off >= 1; off >>= 1) {
        #pragma unroll
        for (int i = 0; i < 2; ++i) {
            #pragma unroll
            for (int r = 0; r < 4; ++r) {
                Dv[i][r] += __shfl_xor(Dv[i][r], off);
                Rv[i][r] += __shfl_xor(Rv[i][r], off);
            }
        }
    }
    if (r16 == 0) {
        #pragma unroll
        for (int i = 0; i < 2; ++i)
            #pragma unroll
            for (int r = 0; r < 4; ++r) {
                int l = lbase + w * 32 + i * 16 + g * 4 + r;
                size_t idx = (size_t)mh * BN * L + (size_t)bn * L + l;
                Dp[idx] = Dv[i][r];
                Rp[idx] = Rv[i][r];
            }
    }
}

// ---------------------------------------------------------------------------
// Kernel 3: res = (R0+R1)/(D0+D1).  32768 elems -> 128 blocks x 256 thr.
// ---------------------------------------------------------------------------
__global__ __launch_bounds__(256)
void combine_kernel(const float* __restrict__ Dp, const float* __restrict__ Rp,
                    float* __restrict__ res)
{
    int i = blockIdx.x * 256 + threadIdx.x;
    float d = Dp[i] + Dp[BN * L + i];
    float r = Rp[i] + Rp[BN * L + i];
    res[i] = r / d;
}

// ---------------------------------------------------------------------------
// Kernel 4: out[b][o][hw] = relu( sum_n w5[o][n] * res[b*4+n][hw] )
// ---------------------------------------------------------------------------
__global__ __launch_bounds__(256)
void out_kernel(const float* __restrict__ res, const float* __restrict__ w5,
                float* __restrict__ out)
{
    const int blk = blockIdx.x;
    const int o = blk & 511;
    const int b = blk >> 9;
    const float4 wv = *(const float4*)&w5[o * 4];

    const float* r0 = res + (size_t)(b * 4 + 0) * L;
    const float* r1 = res + (size_t)(b * 4 + 1) * L;
    const float* r2 = res + (size_t)(b * 4 + 2) * L;
    const float* r3 = res + (size_t)(b * 4 + 3) * L;

    const int hw = threadIdx.x * 4;
    float4 a0 = *(const float4*)&r0[hw];
    float4 a1 = *(const float4*)&r1[hw];
    float4 a2 = *(const float4*)&r2[hw];
    float4 a3 = *(const float4*)&r3[hw];

    float4 ov;
    ov.x = fmaxf(0.f, wv.x * a0.x + wv.y * a1.x + wv.z * a2.x + wv.w * a3.x);
    ov.y = fmaxf(0.f, wv.x * a0.y + wv.y * a1.y + wv.z * a2.y + wv.w * a3.y);
    ov.z = fmaxf(0.f, wv.x * a0.z + wv.y * a1.z + wv.z * a2.z + wv.w * a3.z);
    ov.w = fmaxf(0.f, wv.x * a0.w + wv.y * a1.w + wv.z * a2.w + wv.w * a3.w);

    *(float4*)&out[(size_t)blk * 1024 + hw] = ov;
}

// ---------------------------------------------------------------------------
extern "C" void kernel_launch(void* const* d_in, const int* in_sizes, int n_in,
                              void* d_out, int out_size, void* d_ws, size_t ws_size,
                              hipStream_t stream)
{
    const float* first  = (const float*)d_in[0];
    const float* second = (const float*)d_in[1];
    const float* w1 = (const float*)d_in[2];
    const float* w2 = (const float*)d_in[3];
    const float* w3 = (const float*)d_in[4];
    const float* w4 = (const float*)d_in[5];
    const float* w5 = (const float*)d_in[6];
    float* out = (float*)d_out;

    const size_t projBytes = (size_t)4 * BN * L * Cn * sizeof(unsigned short); // 32 MB
    unsigned short* P = (unsigned short*)d_ws;
    float* Dp  = (float*)((char*)d_ws + projBytes);
    float* Rp  = Dp + 2 * BN * L;
    float* res = Rp + 2 * BN * L;
    unsigned short* whi = (unsigned short*)(res + BN * L);
    unsigned short* wlo = whi + 4 * 16384;

    wsplit_kernel<<<dim3(64), dim3(256), 0, stream>>>(w1, w2, w3, w4, whi, wlo);
    proj_kernel<<<dim3(256), dim3(512), 0, stream>>>(first, second, whi, wlo, P);
    attn_kernel<<<dim3(512), dim3(256), 0, stream>>>(P, Dp, Rp);
    combine_kernel<<<dim3(BN * L / 256), dim3(256), 0, stream>>>(Dp, Rp, res);
    out_kernel<<<dim3(BB * CC), dim3(256), 0, stream>>>(res, w5, out);
}